// Round 1
// baseline (722.423 us; speedup 1.0000x reference)
//
#include <hip/hip_runtime.h>

#define NB 8
#define NS 1024
#define NH 32
#define NKV 8
#define ND 128
#define QT 128
#define KT 64
#define SCALE 0.08838834764831845f

typedef _Float16 f16x8 __attribute__((ext_vector_type(8)));
typedef float f32x4 __attribute__((ext_vector_type(4)));

__global__ __launch_bounds__(256, 2)
void attn_fwd(const float* __restrict__ qg, const float* __restrict__ kg,
              const float* __restrict__ vg, float* __restrict__ og)
{
  __shared__ __align__(16) _Float16 Klds[KT][ND];     // [kv][d], XOR-swizzled rows
  __shared__ __align__(16) _Float16 VTlds[ND][KT];    // [d][kv], XOR-swizzled rows
  __shared__ __align__(16) _Float16 Plds[4][32][72];  // per-wave P, padded stride

  const int tid  = threadIdx.x;
  const int lane = tid & 63;
  const int w    = tid >> 6;
  const int lq   = lane & 15;
  const int lg   = lane >> 4;

  const int qtile = blockIdx.x;
  const int b     = blockIdx.y;
  const int h     = blockIdx.z;
  const int hkv   = h >> 2;

  const int qbase = qtile * QT;
  const int qr0   = qbase + w * 32;

  // ---- load Q fragments (scale folded in, f16) ----
  f16x8 aq[2][4];
#pragma unroll
  for (int rb = 0; rb < 2; ++rb) {
    const float* qp = qg + (size_t)(b * NS + qr0 + rb * 16 + lq) * (NH * ND) + h * ND + lg * 8;
#pragma unroll
    for (int kb = 0; kb < 4; ++kb) {
      float4 f0 = *(const float4*)(qp + kb * 32);
      float4 f1 = *(const float4*)(qp + kb * 32 + 4);
      f16x8 a;
      a[0] = (_Float16)(f0.x * SCALE); a[1] = (_Float16)(f0.y * SCALE);
      a[2] = (_Float16)(f0.z * SCALE); a[3] = (_Float16)(f0.w * SCALE);
      a[4] = (_Float16)(f1.x * SCALE); a[5] = (_Float16)(f1.y * SCALE);
      a[6] = (_Float16)(f1.z * SCALE); a[7] = (_Float16)(f1.w * SCALE);
      aq[rb][kb] = a;
    }
  }

  f32x4 oa[2][8];
  float m_run[2][4], l_run[2][4];
#pragma unroll
  for (int rb = 0; rb < 2; ++rb) {
#pragma unroll
    for (int j = 0; j < 4; ++j) { m_run[rb][j] = -1e30f; l_run[rb][j] = 0.f; }
#pragma unroll
    for (int db = 0; db < 8; ++db) oa[rb][db] = (f32x4){0.f, 0.f, 0.f, 0.f};
  }

  const int nt = (qbase + QT) / KT;   // causal: only tiles up to block diagonal
  for (int ti = 0; ti < nt; ++ti) {
    const int kv0 = ti * KT;

    // ---- stage K tile: 64x128 fp32 -> f16, swizzled ----
#pragma unroll
    for (int it = 0; it < 8; ++it) {
      int f   = tid + it * 256;
      int kvr = f >> 5;
      int d4  = (f & 31) * 4;
      const float4 kk = *(const float4*)(kg + (size_t)(b * NS + kv0 + kvr) * (NKV * ND) + hkv * ND + d4);
      union { _Float16 h4[4]; unsigned long long u; } pk;
      pk.h4[0] = (_Float16)kk.x; pk.h4[1] = (_Float16)kk.y;
      pk.h4[2] = (_Float16)kk.z; pk.h4[3] = (_Float16)kk.w;
      int off = (d4 * 2) ^ ((kvr & 7) << 4);
      *(unsigned long long*)((char*)&Klds[kvr][0] + off) = pk.u;
    }
    // ---- stage V^T: [d][kv] f16, swizzled; kv packed in pairs ----
    {
      int dcol = tid & 127;
      int p0   = tid >> 7;
      const float* vp = vg + (size_t)(b * NS + kv0) * (NKV * ND) + hkv * ND + dcol;
#pragma unroll
      for (int it = 0; it < 16; ++it) {
        int p = p0 + it * 2;                  // kv pair index 0..31
        float v0 = vp[(size_t)(2 * p) * (NKV * ND)];
        float v1 = vp[(size_t)(2 * p + 1) * (NKV * ND)];
        union { _Float16 h2[2]; unsigned u; } pv;
        pv.h2[0] = (_Float16)v0; pv.h2[1] = (_Float16)v1;
        int off = (4 * p) ^ ((dcol & 7) << 4);
        *(unsigned*)((char*)&VTlds[dcol][0] + off) = pv.u;
      }
    }
    __syncthreads();

    if (kv0 <= qr0 + 31) {   // wave-uniform: skip fully-masked tiles
      // ---- S = (Q*scale) K^T ----
      f32x4 s[2][4];
#pragma unroll
      for (int rb = 0; rb < 2; ++rb)
#pragma unroll
        for (int cb = 0; cb < 4; ++cb) s[rb][cb] = (f32x4){0.f, 0.f, 0.f, 0.f};
#pragma unroll
      for (int cb = 0; cb < 4; ++cb) {
        const int kvrow = cb * 16 + lq;
        const char* kbp = (const char*)&Klds[kvrow][0];
        const int swz = (kvrow & 7) << 4;
#pragma unroll
        for (int kb = 0; kb < 4; ++kb) {
          f16x8 bk = *(const f16x8*)(kbp + ((kb * 64 + lg * 16) ^ swz));
#pragma unroll
          for (int rb = 0; rb < 2; ++rb)
            s[rb][cb] = __builtin_amdgcn_mfma_f32_16x16x32_f16(aq[rb][kb], bk, s[rb][cb], 0, 0, 0);
        }
      }
      // ---- causal mask (diagonal tiles only) ----
      if (kv0 + 63 > qr0) {
#pragma unroll
        for (int rb = 0; rb < 2; ++rb) {
          const int row = qr0 + rb * 16 + lg * 4;
#pragma unroll
          for (int cb = 0; cb < 4; ++cb) {
            const int kv = kv0 + cb * 16 + lq;
#pragma unroll
            for (int j = 0; j < 4; ++j)
              if (kv > row + j) s[rb][cb][j] = -1e30f;
          }
        }
      }
      // ---- online softmax (row lives in 16-lane group) ----
      float alpha[2][4];
#pragma unroll
      for (int rb = 0; rb < 2; ++rb) {
#pragma unroll
        for (int j = 0; j < 4; ++j) {
          float t = fmaxf(fmaxf(s[rb][0][j], s[rb][1][j]), fmaxf(s[rb][2][j], s[rb][3][j]));
          t = fmaxf(t, __shfl_xor(t, 1));
          t = fmaxf(t, __shfl_xor(t, 2));
          t = fmaxf(t, __shfl_xor(t, 4));
          t = fmaxf(t, __shfl_xor(t, 8));
          const float mo = m_run[rb][j];
          const float mn = fmaxf(mo, t);
          const float a  = __expf(mo - mn);
          m_run[rb][j] = mn;
          float rs = 0.f;
#pragma unroll
          for (int cb = 0; cb < 4; ++cb) {
            float p = __expf(s[rb][cb][j] - mn);
            s[rb][cb][j] = p;
            rs += p;
          }
          rs += __shfl_xor(rs, 1);
          rs += __shfl_xor(rs, 2);
          rs += __shfl_xor(rs, 4);
          rs += __shfl_xor(rs, 8);
          l_run[rb][j] = l_run[rb][j] * a + rs;
          alpha[rb][j] = a;
        }
      }
#pragma unroll
      for (int rb = 0; rb < 2; ++rb)
#pragma unroll
        for (int db = 0; db < 8; ++db)
#pragma unroll
          for (int j = 0; j < 4; ++j) oa[rb][db][j] *= alpha[rb][j];

      // ---- P -> per-wave LDS (re-shape D-frag -> A-frag) ----
      _Float16* pw = &Plds[w][0][0];
#pragma unroll
      for (int rb = 0; rb < 2; ++rb)
#pragma unroll
        for (int cb = 0; cb < 4; ++cb)
#pragma unroll
          for (int j = 0; j < 4; ++j)
            pw[(rb * 16 + lg * 4 + j) * 72 + cb * 16 + lq] = (_Float16)s[rb][cb][j];

      // ---- O += P V ----
#pragma unroll
      for (int kb = 0; kb < 2; ++kb) {
        f16x8 pa[2];
#pragma unroll
        for (int rb = 0; rb < 2; ++rb)
          pa[rb] = *(const f16x8*)((const char*)&Plds[w][rb * 16 + lq][0] + kb * 64 + lg * 16);
#pragma unroll
        for (int db = 0; db < 8; ++db) {
          const int drow = db * 16 + lq;
          f16x8 vb = *(const f16x8*)((const char*)&VTlds[drow][0] + ((kb * 64 + lg * 16) ^ ((drow & 7) << 4)));
#pragma unroll
          for (int rb = 0; rb < 2; ++rb)
            oa[rb][db] = __builtin_amdgcn_mfma_f32_16x16x32_f16(pa[rb], vb, oa[rb][db], 0, 0, 0);
        }
      }
    }
    __syncthreads();
  }

  // ---- epilogue: O / l, coalesced fp32 stores ----
#pragma unroll
  for (int rb = 0; rb < 2; ++rb) {
    float inv[4];
#pragma unroll
    for (int j = 0; j < 4; ++j) inv[j] = 1.0f / l_run[rb][j];
    const int row = b * NS + qr0 + rb * 16 + lg * 4;
#pragma unroll
    for (int j = 0; j < 4; ++j) {
      float* op = og + (size_t)(row + j) * (NH * ND) + h * ND + lq;
#pragma unroll
      for (int db = 0; db < 8; ++db)
        op[db * 16] = oa[rb][db][j] * inv[j];
    }
  }
}

extern "C" void kernel_launch(void* const* d_in, const int* in_sizes, int n_in,
                              void* d_out, int out_size, void* d_ws, size_t ws_size,
                              hipStream_t stream) {
  const float* q = (const float*)d_in[0];
  const float* k = (const float*)d_in[1];
  const float* v = (const float*)d_in[2];
  float* o = (float*)d_out;
  dim3 grid(NS / QT, NB, NH);
  attn_fwd<<<grid, 256, 0, stream>>>(q, k, v, o);
}

// Round 4
// 235.766 us; speedup vs baseline: 3.0642x; 3.0642x over previous
//
#include <hip/hip_runtime.h>

#define NB 8
#define NS 1024
#define NH 32
#define NKV 8
#define ND 128
#define QT 256     // per block: 8 waves x 32 q-rows
#define KT 64

typedef _Float16 f16x8 __attribute__((ext_vector_type(8)));
typedef _Float16 f16x4 __attribute__((ext_vector_type(4)));
typedef _Float16 f16x2 __attribute__((ext_vector_type(2)));
typedef __fp16 fp16x2 __attribute__((ext_vector_type(2)));
typedef float f32x16 __attribute__((ext_vector_type(16)));
typedef unsigned int u32x2 __attribute__((ext_vector_type(2)));

__device__ __forceinline__ float exp2fast(float x) { return __builtin_amdgcn_exp2f(x); }

__device__ __forceinline__ unsigned pkrtz_u(float a, float b) {
  union { fp16x2 h; unsigned u; } c;
  c.h = __builtin_amdgcn_cvt_pkrtz(a, b);
  return c.u;
}
// exchange with lane^32 partner: returns (lo-half word, hi-half word)
__device__ __forceinline__ u32x2 swap32(float x) {
  union { float f; unsigned u; } c; c.f = x;
  return __builtin_amdgcn_permlane32_swap(c.u, c.u, false, false);
}
__device__ __forceinline__ float asf(unsigned u) { union { unsigned u; float f; } c; c.u = u; return c.f; }

__global__ __launch_bounds__(512, 1)
void attn_fwd(const float* __restrict__ qg, const float* __restrict__ kg,
              const float* __restrict__ vg, float* __restrict__ og)
{
  // K: 64 rows x 256B, swizzle byte ^= (kv&15)<<4   (within-row)
  __shared__ __align__(16) _Float16 Klds[KT * 128];
  // V^T: 128 d-rows x 256B (kv*2 bytes used, XOR spills into upper half), swizzle key g(d)=(d^(d>>2))&15
  __shared__ __align__(16) _Float16 VTlds[128 * 128];

  const int tid  = threadIdx.x;
  const int lane = tid & 63;
  const int w    = tid >> 6;
  const int lq   = lane & 31;
  const int hi   = lane >> 5;

  const int qtile = blockIdx.x;   // 0..3
  const int b     = blockIdx.y;
  const int h     = blockIdx.z;
  const int hkv   = h >> 2;

  const int qr0w = qtile * QT + w * 32;
  const int qrow = qr0w + lq;       // this lane's softmax row

  const float QS = 0.08838834764831845f * 1.4426950408889634f;  // scale * log2(e)

  // ---- Q fragments (B-frag: col=q=lane&31, k = 8*hi + i per 16-d block) ----
  f16x8 qf[8];
  {
    const float* qp = qg + (size_t)(b * NS + qrow) * (NH * ND) + h * ND + hi * 8;
#pragma unroll
    for (int dblk = 0; dblk < 8; ++dblk) {
      float4 f0 = *(const float4*)(qp + dblk * 16);
      float4 f1 = *(const float4*)(qp + dblk * 16 + 4);
      f16x8 a;
      a[0] = (_Float16)(f0.x * QS); a[1] = (_Float16)(f0.y * QS);
      a[2] = (_Float16)(f0.z * QS); a[3] = (_Float16)(f0.w * QS);
      a[4] = (_Float16)(f1.x * QS); a[5] = (_Float16)(f1.y * QS);
      a[6] = (_Float16)(f1.z * QS); a[7] = (_Float16)(f1.w * QS);
      qf[dblk] = a;
    }
  }

  f32x16 acc[4];
#pragma unroll
  for (int nb = 0; nb < 4; ++nb)
#pragma unroll
    for (int r = 0; r < 16; ++r) acc[nb][r] = 0.f;
  float m_run = -1e30f, l_run = 0.f;

  const float* kbase0 = kg + (size_t)(b * NS) * (NKV * ND) + hkv * ND;
  const float* vbase0 = vg + (size_t)(b * NS) * (NKV * ND) + hkv * ND;

  const int nt = (qtile + 1) * (QT / KT);
  for (int ti = 0; ti < nt; ++ti) {
    const int kv0 = ti * KT;

    // ---- stage K tile (64x128 f32 -> f16, swizzled) ----
    const float* kb_ = kbase0 + (size_t)kv0 * (NKV * ND);
#pragma unroll
    for (int it = 0; it < 4; ++it) {
      int f   = tid + it * 512;
      int kvr = f >> 5;
      int d4  = (f & 31) * 4;
      float4 kk = *(const float4*)(kb_ + (size_t)kvr * (NKV * ND) + d4);
      union { f16x4 h; unsigned long long u; } pk;
      pk.h[0] = (_Float16)kk.x; pk.h[1] = (_Float16)kk.y;
      pk.h[2] = (_Float16)kk.z; pk.h[3] = (_Float16)kk.w;
      int off = kvr * 256 + ((d4 * 2) ^ ((kvr & 15) << 4));
      *(unsigned long long*)((char*)Klds + off) = pk.u;
    }
    // ---- stage V^T (pair-kv loads -> b32 transposed writes, swizzled) ----
    const float* vb_ = vbase0 + (size_t)kv0 * (NKV * ND);
#pragma unroll
    for (int it = 0; it < 2; ++it) {
      int f   = tid + it * 512;
      int kvp = f >> 5;              // kv pair 0..31
      int d4  = (f & 31) * 4;
      float4 v0 = *(const float4*)(vb_ + (size_t)(2 * kvp) * (NKV * ND) + d4);
      float4 v1 = *(const float4*)(vb_ + (size_t)(2 * kvp + 1) * (NKV * ND) + d4);
      float e0[4] = {v0.x, v0.y, v0.z, v0.w};
      float e1[4] = {v1.x, v1.y, v1.z, v1.w};
#pragma unroll
      for (int i = 0; i < 4; ++i) {
        int d = d4 + i;
        union { f16x2 h; unsigned u; } pv;
        pv.h[0] = (_Float16)e0[i]; pv.h[1] = (_Float16)e1[i];
        int off = d * 256 + ((kvp * 4) ^ (((d ^ (d >> 2)) & 15) << 4));
        *(unsigned*)((char*)VTlds + off) = pv.u;
      }
    }
    __syncthreads();

    if (kv0 <= qr0w + 31) {          // wave-uniform causal tile skip
      // ---- swapped QK^T: P^T[kv][q] ----
      f32x16 s[2];
#pragma unroll
      for (int r = 0; r < 16; ++r) { s[0][r] = 0.f; s[1][r] = 0.f; }
#pragma unroll
      for (int dblk = 0; dblk < 8; ++dblk) {
        int soff = (dblk * 32 + 16 * hi) ^ ((lq & 15) << 4);
        f16x8 k0 = *(const f16x8*)((const char*)Klds + lq * 256 + soff);
        f16x8 k1 = *(const f16x8*)((const char*)Klds + (lq + 32) * 256 + soff);
        s[0] = __builtin_amdgcn_mfma_f32_32x32x16_f16(k0, qf[dblk], s[0], 0, 0, 0);
        s[1] = __builtin_amdgcn_mfma_f32_32x32x16_f16(k1, qf[dblk], s[1], 0, 0, 0);
      }
      // ---- causal mask (diagonal tiles only) ----
      if (kv0 + KT - 1 > qr0w) {
        const int thr = qrow - kv0;  // keep kv_local <= thr
#pragma unroll
        for (int kb = 0; kb < 2; ++kb)
#pragma unroll
          for (int r = 0; r < 16; ++r) {
            int kvl = kb * 32 + (r & 3) + 8 * (r >> 2) + 4 * hi;
            if (kvl > thr) s[kb][r] = -1e30f;
          }
      }
      // ---- online softmax (in-lane + one permlane swap) ----
      float pmax = s[0][0];
#pragma unroll
      for (int r = 1; r < 16; ++r) pmax = fmaxf(pmax, s[0][r]);
#pragma unroll
      for (int r = 0; r < 16; ++r) pmax = fmaxf(pmax, s[1][r]);
      {
        u32x2 pr = swap32(pmax);
        pmax = fmaxf(asf(pr[0]), asf(pr[1]));
      }
      const float mn = fmaxf(m_run, pmax);
      const float al = exp2fast(m_run - mn);
      m_run = mn;
      float rs = 0.f;
#pragma unroll
      for (int kb = 0; kb < 2; ++kb)
#pragma unroll
        for (int r = 0; r < 16; ++r) {
          float p = exp2fast(s[kb][r] - mn);
          s[kb][r] = p;
          rs += p;
        }
      {
        u32x2 sr = swap32(rs);
        rs = asf(sr[0]) + asf(sr[1]);
      }
      l_run = l_run * al + rs;
      // ---- rescale O (alpha broadcast row-stat -> acc rows) ----
      float albc[16];
#pragma unroll
      for (int r = 0; r < 16; ++r) {
        int row = (r & 3) + 8 * (r >> 2) + 4 * hi;
        albc[r] = __shfl(al, row, 64);
      }
#pragma unroll
      for (int nb = 0; nb < 4; ++nb)
#pragma unroll
        for (int r = 0; r < 16; ++r) acc[nb][r] *= albc[r];
      // ---- P -> A-fragments in-register (cvt_pk + permlane32_swap) ----
      f16x8 pa[4];
#pragma unroll
      for (int t = 0; t < 4; ++t) {
        const int kb = t >> 1, rb = (t & 1) * 8;
        unsigned w0 = pkrtz_u(s[kb][rb + 0], s[kb][rb + 1]);
        unsigned w1 = pkrtz_u(s[kb][rb + 2], s[kb][rb + 3]);
        unsigned w2 = pkrtz_u(s[kb][rb + 4], s[kb][rb + 5]);
        unsigned w3 = pkrtz_u(s[kb][rb + 6], s[kb][rb + 7]);
        u32x2 p02 = __builtin_amdgcn_permlane32_swap(w0, w2, false, false);
        u32x2 p13 = __builtin_amdgcn_permlane32_swap(w1, w3, false, false);
        union { unsigned u[4]; f16x8 v; } pw;
        pw.u[0] = p02[0]; pw.u[1] = p13[0]; pw.u[2] = p02[1]; pw.u[3] = p13[1];
        pa[t] = pw.v;
      }
      // ---- O += P V ----
#pragma unroll
      for (int t = 0; t < 4; ++t) {
        int koff = t * 32 + 16 * hi;
#pragma unroll
        for (int nb = 0; nb < 4; ++nb) {
          int d = nb * 32 + lq;
          int off = d * 256 + (koff ^ (((d ^ (d >> 2)) & 15) << 4));
          f16x8 vb = *(const f16x8*)((const char*)VTlds + off);
          acc[nb] = __builtin_amdgcn_mfma_f32_32x32x16_f16(pa[t], vb, acc[nb], 0, 0, 0);
        }
      }
    }
    __syncthreads();
  }

  // ---- epilogue: divide by l, coalesced f32 stores ----
  const float linv = 1.0f / l_run;
  float lbc[16];
#pragma unroll
  for (int r = 0; r < 16; ++r) {
    int row = (r & 3) + 8 * (r >> 2) + 4 * hi;
    lbc[r] = __shfl(linv, row, 64);
  }
#pragma unroll
  for (int r = 0; r < 16; ++r) {
    int row = qr0w + (r & 3) + 8 * (r >> 2) + 4 * hi;
    float* op = og + (size_t)(b * NS + row) * (NH * ND) + h * ND + lq;
#pragma unroll
    for (int nb = 0; nb < 4; ++nb)
      op[nb * 32] = acc[nb][r] * lbc[r];
  }
}

extern "C" void kernel_launch(void* const* d_in, const int* in_sizes, int n_in,
                              void* d_out, int out_size, void* d_ws, size_t ws_size,
                              hipStream_t stream) {
  const float* q = (const float*)d_in[0];
  const float* k = (const float*)d_in[1];
  const float* v = (const float*)d_in[2];
  float* o = (float*)d_out;
  dim3 grid(NS / QT, NB, NH);
  attn_fwd<<<grid, 512, 0, stream>>>(q, k, v, o);
}

// Round 5
// 191.631 us; speedup vs baseline: 3.7699x; 1.2303x over previous
//
#include <hip/hip_runtime.h>

#define NB 8
#define NS 1024
#define NH 32
#define NKV 8
#define ND 128
#define QT 256     // per block: 8 waves x 32 q-rows
#define KT 64

typedef _Float16 f16x8 __attribute__((ext_vector_type(8)));
typedef _Float16 f16x4 __attribute__((ext_vector_type(4)));
typedef _Float16 f16x2 __attribute__((ext_vector_type(2)));
typedef __fp16 fp16x2 __attribute__((ext_vector_type(2)));
typedef float f32x16 __attribute__((ext_vector_type(16)));
typedef unsigned int u32x2 __attribute__((ext_vector_type(2)));

__device__ __forceinline__ float exp2fast(float x) { return __builtin_amdgcn_exp2f(x); }

__device__ __forceinline__ unsigned pkrtz_u(float a, float b) {
  union { fp16x2 h; unsigned u; } c;
  c.h = __builtin_amdgcn_cvt_pkrtz(a, b);
  return c.u;
}
__device__ __forceinline__ u32x2 swap32(float x) {
  union { float f; unsigned u; } c; c.f = x;
  return __builtin_amdgcn_permlane32_swap(c.u, c.u, false, false);
}
__device__ __forceinline__ float asf(unsigned u) { union { unsigned u; float f; } c; c.u = u; return c.f; }
__device__ __forceinline__ int gsw(int d) { return ((d ^ (d >> 2)) & 15) << 4; }

__global__ __launch_bounds__(512, 1)
void attn_fwd(const float* __restrict__ qg, const float* __restrict__ kg,
              const float* __restrict__ vg, float* __restrict__ og)
{
  // double-buffered: K 2x16KB (64 rows x 256B, byte ^= (kv&15)<<4),
  //                  V^T 2x32KB (128 d-rows x 256B, chunk ^= gsw(d))
  __shared__ __align__(16) _Float16 Klds[2][KT * 128];
  __shared__ __align__(16) _Float16 VTlds[2][128 * 128];

  const int tid  = threadIdx.x;
  const int lane = tid & 63;
  const int w    = tid >> 6;
  const int lq   = lane & 31;
  const int hi   = lane >> 5;

  const int qtile = blockIdx.x;   // 0..3
  const int b     = blockIdx.y;
  const int h     = blockIdx.z;
  const int hkv   = h >> 2;

  const int qr0w = qtile * QT + w * 32;
  const int qrow = qr0w + lq;

  const float QS = 0.08838834764831845f * 1.4426950408889634f;  // scale * log2(e)

  // ---- Q fragments (B-frag: col=q=lane&31, k = 8*hi + i per 16-d block) ----
  f16x8 qf[8];
  {
    const float* qp = qg + (size_t)(b * NS + qrow) * (NH * ND) + h * ND + hi * 8;
#pragma unroll
    for (int dblk = 0; dblk < 8; ++dblk) {
      float4 f0 = *(const float4*)(qp + dblk * 16);
      float4 f1 = *(const float4*)(qp + dblk * 16 + 4);
      f16x8 a;
      a[0] = (_Float16)(f0.x * QS); a[1] = (_Float16)(f0.y * QS);
      a[2] = (_Float16)(f0.z * QS); a[3] = (_Float16)(f0.w * QS);
      a[4] = (_Float16)(f1.x * QS); a[5] = (_Float16)(f1.y * QS);
      a[6] = (_Float16)(f1.z * QS); a[7] = (_Float16)(f1.w * QS);
      qf[dblk] = a;
    }
  }

  f32x16 acc[4];
#pragma unroll
  for (int nb = 0; nb < 4; ++nb)
#pragma unroll
    for (int r = 0; r < 16; ++r) acc[nb][r] = 0.f;
  float m_run = -1e30f, l_run = 0.f;

  const float* kbase0 = kg + (size_t)(b * NS) * (NKV * ND) + hkv * ND;
  const float* vbase0 = vg + (size_t)(b * NS) * (NKV * ND) + hkv * ND;

  const int kvq_s = tid >> 5;          // staging decomposition for V (quad of kv rows)
  const int d4_s  = (tid & 31) * 4;

  float kpre[4][4], vpre[4][4];        // in-flight prefetch registers

#define ISSUE_TILE(KV0)                                                              \
  {                                                                                  \
    const float* kb_ = kbase0 + (size_t)(KV0) * (NKV * ND);                          \
    _Pragma("unroll")                                                                \
    for (int it = 0; it < 4; ++it) {                                                 \
      int f = tid + it * 512;                                                        \
      float4 t = *(const float4*)(kb_ + (size_t)(f >> 5) * (NKV * ND) + (f & 31) * 4); \
      kpre[it][0] = t.x; kpre[it][1] = t.y; kpre[it][2] = t.z; kpre[it][3] = t.w;    \
    }                                                                                \
    const float* vb_ = vbase0 + (size_t)(KV0) * (NKV * ND);                          \
    _Pragma("unroll")                                                                \
    for (int r = 0; r < 4; ++r) {                                                    \
      float4 t = *(const float4*)(vb_ + (size_t)(4 * kvq_s + r) * (NKV * ND) + d4_s); \
      vpre[r][0] = t.x; vpre[r][1] = t.y; vpre[r][2] = t.z; vpre[r][3] = t.w;        \
    }                                                                                \
  }

#define WRITE_TILE(BUF)                                                              \
  {                                                                                  \
    char* Kb = (char*)&Klds[BUF][0];                                                 \
    _Pragma("unroll")                                                                \
    for (int it = 0; it < 4; ++it) {                                                 \
      int f = tid + it * 512; int kvr = f >> 5; int d4 = (f & 31) * 4;               \
      union { f16x4 h; unsigned long long u; } pk;                                   \
      pk.h[0] = (_Float16)kpre[it][0]; pk.h[1] = (_Float16)kpre[it][1];              \
      pk.h[2] = (_Float16)kpre[it][2]; pk.h[3] = (_Float16)kpre[it][3];              \
      *(unsigned long long*)(Kb + kvr * 256 + ((d4 * 2) ^ ((kvr & 15) << 4))) = pk.u; \
    }                                                                                \
    char* Vb = (char*)&VTlds[BUF][0];                                                \
    _Pragma("unroll")                                                                \
    for (int i = 0; i < 4; ++i) {                                                    \
      int d = d4_s + i;                                                              \
      union { f16x4 h; unsigned long long u; } pv;                                   \
      pv.h[0] = (_Float16)vpre[0][i]; pv.h[1] = (_Float16)vpre[1][i];                \
      pv.h[2] = (_Float16)vpre[2][i]; pv.h[3] = (_Float16)vpre[3][i];                \
      *(unsigned long long*)(Vb + d * 256 + ((kvq_s * 8) ^ gsw(d))) = pv.u;          \
    }                                                                                \
  }

  const int nt = (qtile + 1) * (QT / KT);

  // ---- prologue: stage tile 0 into buffer 0 ----
  ISSUE_TILE(0);
  WRITE_TILE(0);
  __syncthreads();

  for (int ti = 0; ti < nt; ++ti) {
    const int kv0 = ti * KT;
    const int cur = ti & 1;
    const bool hn = (ti + 1 < nt);

    if (hn) ISSUE_TILE(kv0 + KT);     // T14: loads in flight under compute

    if (kv0 <= qr0w + 31) {           // wave-uniform causal tile skip
      const char* Kb = (const char*)&Klds[cur][0];
      const char* Vb = (const char*)&VTlds[cur][0];

      // ---- swapped QK^T: P^T[kv][q] ----
      f32x16 s[2];
#pragma unroll
      for (int r = 0; r < 16; ++r) { s[0][r] = 0.f; s[1][r] = 0.f; }
      __builtin_amdgcn_s_setprio(1);
#pragma unroll
      for (int dblk = 0; dblk < 8; ++dblk) {
        int soff = (dblk * 32 + 16 * hi) ^ ((lq & 15) << 4);
        f16x8 k0 = *(const f16x8*)(Kb + lq * 256 + soff);
        f16x8 k1 = *(const f16x8*)(Kb + (lq + 32) * 256 + soff);
        s[0] = __builtin_amdgcn_mfma_f32_32x32x16_f16(k0, qf[dblk], s[0], 0, 0, 0);
        s[1] = __builtin_amdgcn_mfma_f32_32x32x16_f16(k1, qf[dblk], s[1], 0, 0, 0);
      }
      __builtin_amdgcn_s_setprio(0);

      // ---- causal mask (diagonal tiles only) ----
      if (kv0 + KT - 1 > qr0w) {
        const int thr = qrow - kv0;
#pragma unroll
        for (int kb = 0; kb < 2; ++kb)
#pragma unroll
          for (int r = 0; r < 16; ++r) {
            int kvl = kb * 32 + (r & 3) + 8 * (r >> 2) + 4 * hi;
            if (kvl > thr) s[kb][r] = -1e30f;
          }
      }

      // ---- online softmax with defer-max (T13, THR=8 in log2 units) ----
      float pmax = s[0][0];
#pragma unroll
      for (int r = 1; r < 16; ++r) pmax = fmaxf(pmax, s[0][r]);
#pragma unroll
      for (int r = 0; r < 16; ++r) pmax = fmaxf(pmax, s[1][r]);
      {
        u32x2 pr = swap32(pmax);
        pmax = fmaxf(asf(pr[0]), asf(pr[1]));
      }
      const int need = !__all(pmax <= m_run + 8.0f);
      float al = 1.0f;
      if (need) {
        const float mn = fmaxf(m_run, pmax);
        al = exp2fast(m_run - mn);
        m_run = mn;
      }
      float rs = 0.f;
#pragma unroll
      for (int kb = 0; kb < 2; ++kb)
#pragma unroll
        for (int r = 0; r < 16; ++r) {
          float p = exp2fast(s[kb][r] - m_run);
          s[kb][r] = p;
          rs += p;
        }
      {
        u32x2 sr = swap32(rs);
        rs = asf(sr[0]) + asf(sr[1]);
      }
      if (need) {
        float albc[16];
#pragma unroll
        for (int r = 0; r < 16; ++r) {
          int row = (r & 3) + 8 * (r >> 2) + 4 * hi;
          albc[r] = __shfl(al, row, 64);
        }
#pragma unroll
        for (int nb = 0; nb < 4; ++nb)
#pragma unroll
          for (int r = 0; r < 16; ++r) acc[nb][r] *= albc[r];
        l_run = l_run * al + rs;
      } else {
        l_run += rs;
      }

      // ---- P -> A-fragments in-register (cvt_pk + permlane32_swap) ----
      f16x8 pa[4];
#pragma unroll
      for (int t = 0; t < 4; ++t) {
        const int kb = t >> 1, rb = (t & 1) * 8;
        unsigned w0 = pkrtz_u(s[kb][rb + 0], s[kb][rb + 1]);
        unsigned w1 = pkrtz_u(s[kb][rb + 2], s[kb][rb + 3]);
        unsigned w2 = pkrtz_u(s[kb][rb + 4], s[kb][rb + 5]);
        unsigned w3 = pkrtz_u(s[kb][rb + 6], s[kb][rb + 7]);
        u32x2 p02 = __builtin_amdgcn_permlane32_swap(w0, w2, false, false);
        u32x2 p13 = __builtin_amdgcn_permlane32_swap(w1, w3, false, false);
        union { unsigned u[4]; f16x8 v; } pw;
        pw.u[0] = p02[0]; pw.u[1] = p13[0]; pw.u[2] = p02[1]; pw.u[3] = p13[1];
        pa[t] = pw.v;
      }

      // ---- O += P V ----
      __builtin_amdgcn_s_setprio(1);
#pragma unroll
      for (int t = 0; t < 4; ++t) {
        int koff = t * 32 + 16 * hi;
#pragma unroll
        for (int nb = 0; nb < 4; ++nb) {
          int d = nb * 32 + lq;
          f16x8 vb = *(const f16x8*)(Vb + d * 256 + (koff ^ gsw(d)));
          acc[nb] = __builtin_amdgcn_mfma_f32_32x32x16_f16(pa[t], vb, acc[nb], 0, 0, 0);
        }
      }
      __builtin_amdgcn_s_setprio(0);
    }

    if (hn) WRITE_TILE(cur ^ 1);      // into the other buffer; no WAR with compute(cur)
    __syncthreads();                  // one barrier per tile
  }

  // ---- epilogue: divide by l, coalesced f32 stores ----
  const float linv = 1.0f / l_run;
  float lbc[16];
#pragma unroll
  for (int r = 0; r < 16; ++r) {
    int row = (r & 3) + 8 * (r >> 2) + 4 * hi;
    lbc[r] = __shfl(linv, row, 64);
  }
#pragma unroll
  for (int r = 0; r < 16; ++r) {
    int row = qr0w + (r & 3) + 8 * (r >> 2) + 4 * hi;
    float* op = og + (size_t)(b * NS + row) * (NH * ND) + h * ND + lq;
#pragma unroll
    for (int nb = 0; nb < 4; ++nb)
      op[nb * 32] = acc[nb][r] * lbc[r];
  }
}

extern "C" void kernel_launch(void* const* d_in, const int* in_sizes, int n_in,
                              void* d_out, int out_size, void* d_ws, size_t ws_size,
                              hipStream_t stream) {
  const float* q = (const float*)d_in[0];
  const float* k = (const float*)d_in[1];
  const float* v = (const float*)d_in[2];
  float* o = (float*)d_out;
  dim3 grid(NS / QT, NB, NH);
  attn_fwd<<<grid, 512, 0, stream>>>(q, k, v, o);
}